// Round 7
// baseline (102.203 us; speedup 1.0000x reference)
//
#include <hip/hip_runtime.h>
#include <hip/hip_bf16.h>
#include <math.h>

typedef __bf16 bf16x8 __attribute__((ext_vector_type(8)));
typedef float  f32x4  __attribute__((ext_vector_type(4)));
typedef unsigned short u16x8 __attribute__((ext_vector_type(8)));

#define B_      16
#define LIN_    32768
#define LOUT_   32760
#define CIN_    21
#define CPAD_   24      // padded channels: row = 48B, 16B-aligned for b128
#define KT_     9
#define F_      128
#define KSTEPS_ 7       // R = 9*24 = 216 -> 7 x 32
#define TILE_L_ 128     // output rows per main block
#define ROWS_   136     // staged rows (128 + 8 overlap)
#define ROWSA_  138     // + 2 zero guard rows
#define NTILE_  256     // tiles per batch: 256*128 = 32768 covers 32760
// ws layout: Wp (bf16 fragments) at offset 0
#define WP_SHORTS_ (4 * KSTEPS_ * 2 * 4 * 16 * 8)   // wv,t,nf,q,la,j = 28672

__device__ __forceinline__ unsigned short f2bf(float f) {
  unsigned u = __float_as_uint(f);
  u += 0x7FFFu + ((u >> 16) & 1u);   // RNE
  return (unsigned short)(u >> 16);
}

// lgkmcnt-only barrier: does NOT drain vmem queues (loads/stores stay in flight)
__device__ __forceinline__ void bar_lds() {
  asm volatile("s_waitcnt lgkmcnt(0)" ::: "memory");
  __builtin_amdgcn_s_barrier();
}

// ---------------- prep: W fragment packing only (4 tiny blocks) ----------------
__global__ __launch_bounds__(256)
void ckn1d_prep(const float* __restrict__ W, float* __restrict__ ws)
{
  const int tid = threadIdx.x;
  const int wv  = blockIdx.x;              // 0..3
  unsigned short* Wp = (unsigned short*)ws;
  for (int idx = tid; idx < KSTEPS_ * 2 * 4 * 16; idx += 256) {
    int t   = idx >> 7;
    int rem = idx & 127;
    int nf  = rem >> 6;
    int q   = (rem >> 4) & 3;
    int la  = rem & 15;
    u16x8 v;
    #pragma unroll
    for (int j = 0; j < 8; ++j) {
      int r = t * 32 + q * 8 + j;
      int k = r / CPAD_;
      int c = r - k * CPAD_;
      float w = 0.f;
      if (c < CIN_ && k < KT_) w = W[(k * CIN_ + c) * F_ + wv * 32 + nf * 16 + la];
      v[j] = f2bf(w);
    }
    *(u16x8*)&Wp[(size_t)((((wv * KSTEPS_ + t) * 2 + nf) * 4 + q) * 16 + la) * 8] = v;
  }
}

// -------- main: stage + in-staging energy + MFMA + direct store --------
__global__ __launch_bounds__(256, 4)
void ckn1d_main(const float* __restrict__ X, const float* __restrict__ ws,
                const float* __restrict__ scale_p, const float* __restrict__ bias_p,
                float* __restrict__ Y)
{
  __shared__ __align__(16) unsigned short tileA[ROWSA_ * CPAD_]; // 6624 B
  __shared__ float rowsq[ROWS_];                                 //  544 B
  __shared__ __align__(16) float inv_s[TILE_L_];                 //  512 B

  const int tid  = threadIdx.x;
  const int wv   = tid >> 6;
  const int lane = tid & 63;
  const int la   = lane & 15;
  const int q    = lane >> 4;

  const int bx   = blockIdx.x;
  const int b    = bx >> 8;
  const int tile = bx & (NTILE_ - 1);
  const int l0t  = tile * TILE_L_;

  const int f0 = wv * 32 + la;
  const float scale = scale_p[0];
  const float bias0 = bias_p[f0];
  const float bias1 = bias_p[f0 + 16];

  const float* __restrict__ Xb = X + (size_t)b * LIN_ * CIN_;
  const unsigned short* __restrict__ Wp = (const unsigned short*)ws;
  float* __restrict__ Yb = Y + (size_t)b * LOUT_ * F_;

  // ---- phase 0: zero rowsq + pad columns + guard rows ----
  if (tid < ROWS_) rowsq[tid] = 0.f;
  for (int i = tid; i < ROWSA_ * 3; i += 256) {
    int r = i / 3;
    tileA[r * CPAD_ + CIN_ + (i - r * 3)] = 0;
  }
  for (int i = tid; i < 2 * CIN_; i += 256) {
    int r = ROWS_ + i / CIN_;
    tileA[r * CPAD_ + (i % CIN_)] = 0;
  }

  // ---- B fragments: 14 coalesced 16B loads from L2-hot Wp (in flight
  // across the lgkm-only barriers) ----
  u16x8 bw[KSTEPS_][2];
  #pragma unroll
  for (int t = 0; t < KSTEPS_; ++t)
    #pragma unroll
    for (int nf = 0; nf < 2; ++nf)
      bw[t][nf] = *(const u16x8*)&Wp[(size_t)((((wv * KSTEPS_ + t) * 2 + nf) * 4 + q) * 16 + la) * 8];

  bar_lds();   // zeros visible before any ds_add

  // ---- phase 1: stage X (coalesced float4 -> bf16 LDS) + energy atomics ----
  {
    const float4* src4 = (const float4*)(Xb + (size_t)l0t * CIN_);
    const int n4v = (min(ROWS_, LIN_ - l0t) * CIN_) >> 2;
    for (int i4 = tid; i4 < (ROWS_ * CIN_) / 4; i4 += 256) {
      float4 v;
      if (i4 < n4v) v = src4[i4];
      else          v = make_float4(0.f, 0.f, 0.f, 0.f);
      int base = i4 * 4;
      int r0 = base / CIN_;          // row of first element
      float s0 = 0.f, s1 = 0.f;      // partial sums for row r0 / r0+1
      #pragma unroll
      for (int e = 0; e < 4; ++e) {
        int idx = base + e;
        int r = idx / CIN_;
        int c = idx - r * CIN_;
        float x = (e == 0) ? v.x : (e == 1) ? v.y : (e == 2) ? v.z : v.w;
        tileA[r * CPAD_ + c] = f2bf(x);
        if (r == r0) s0 += x * x; else s1 += x * x;
      }
      atomicAdd(&rowsq[r0], s0);                       // ds_add_f32
      if (s1 != 0.f && r0 + 1 < ROWS_) atomicAdd(&rowsq[r0 + 1], s1);
    }
  }
  bar_lds();   // tileA + rowsq complete

  // ---- phase 2: inv_s[128] from sliding 9-row energy ----
  if (tid < TILE_L_) {
    float e = 0.f;
    #pragma unroll
    for (int t = 0; t < KT_; ++t) e += rowsq[tid + t];
    inv_s[tid] = scale / (sqrtf(e + 1e-5f) + 1e-5f);
  }
  bar_lds();   // inv_s visible

  // ---- phase 3: barrier-free mf loop: ds_read + MFMA + direct stores ----
  const f32x4 fzero = {0.f, 0.f, 0.f, 0.f};
  const bool full = (l0t + TILE_L_) <= LOUT_;

  #pragma unroll 1
  for (int mf = 0; mf < TILE_L_ / 16; ++mf) {
    const unsigned short* arow = &tileA[(mf * 16 + la) * CPAD_ + q * 8];
    f32x4 a0 = fzero, a1 = fzero;
    #pragma unroll
    for (int t = 0; t < KSTEPS_; ++t) {
      bf16x8 a = *(const bf16x8*)&arow[t * 32];
      a0 = __builtin_amdgcn_mfma_f32_16x16x32_bf16(
          a, __builtin_bit_cast(bf16x8, bw[t][0]), a0, 0, 0, 0);
      a1 = __builtin_amdgcn_mfma_f32_16x16x32_bf16(
          a, __builtin_bit_cast(bf16x8, bw[t][1]), a1, 0, 0, 0);
    }
    const int lrow0 = mf * 16 + q * 4;
    const f32x4 iv4 = *(const f32x4*)&inv_s[lrow0];   // aligned LDS b128
    float* yo = Yb + (size_t)(l0t + lrow0) * F_ + f0;
    if (full) {
      #pragma unroll
      for (int rg = 0; rg < 4; ++rg) {
        float iv = iv4[rg];
        yo[(size_t)rg * F_]      = a0[rg] * iv + bias0;
        yo[(size_t)rg * F_ + 16] = a1[rg] * iv + bias1;
      }
    } else {
      #pragma unroll
      for (int rg = 0; rg < 4; ++rg) {
        float iv = iv4[rg];
        if (l0t + lrow0 + rg < LOUT_) {
          yo[(size_t)rg * F_]      = a0[rg] * iv + bias0;
          yo[(size_t)rg * F_ + 16] = a1[rg] * iv + bias1;
        }
      }
    }
  }
}

extern "C" void kernel_launch(void* const* d_in, const int* in_sizes, int n_in,
                              void* d_out, int out_size, void* d_ws, size_t ws_size,
                              hipStream_t stream) {
  const float* X  = (const float*)d_in[0];
  const float* W  = (const float*)d_in[1];
  const float* S  = (const float*)d_in[2];
  const float* Bi = (const float*)d_in[3];
  float* Y  = (float*)d_out;
  float* ws = (float*)d_ws;

  ckn1d_prep<<<dim3(4), dim3(256), 0, stream>>>(W, ws);
  ckn1d_main<<<dim3(B_ * NTILE_), dim3(256), 0, stream>>>(X, ws, S, Bi, Y);
}

// Round 8
// 69.093 us; speedup vs baseline: 1.4792x; 1.4792x over previous
//
#include <hip/hip_runtime.h>
#include <hip/hip_bf16.h>
#include <math.h>

typedef __bf16 bf16x8 __attribute__((ext_vector_type(8)));
typedef float  f32x4  __attribute__((ext_vector_type(4)));
typedef unsigned short u16x8 __attribute__((ext_vector_type(8)));

#define B_      16
#define LIN_    32768
#define LOUT_   32760
#define CIN_    21
#define CPAD_   24      // padded channels: row = 48B, 16B-aligned for b128
#define KT_     9
#define F_      128
#define KSTEPS_ 7       // R = 9*24 = 216 -> 7 x 32
#define TILE_L_ 128     // output rows per main block
#define ROWS_   136     // staged rows (128 + 8 overlap)
#define ROWSA_  138     // + 2 zero guard rows
#define NTILE_  256     // tiles per batch: 256*128 = 32768 covers 32760
#define LPAD_   32768   // per-batch inv_s stride in ws (padded)
#define OBST_   136     // outbuf row stride in floats (544B, 16B-aligned)
// prep: inv blocks
#define IB_ROWS_ 1024
#define IB_PER_B 32
// ws layout: [0, 16*32768) floats = inv_s ; then Wp (bf16 fragments)
#define WP_OFF_FLOATS_ (B_ * LPAD_)

__device__ __forceinline__ unsigned short f2bf(float f) {
  unsigned u = __float_as_uint(f);
  u += 0x7FFFu + ((u >> 16) & 1u);   // RNE
  return (unsigned short)(u >> 16);
}

// lgkmcnt-only barrier: does NOT drain vmem queues (stores stay in flight)
__device__ __forceinline__ void bar_lds() {
  asm volatile("s_waitcnt lgkmcnt(0)" ::: "memory");
  __builtin_amdgcn_s_barrier();
}

// ---------------- prep: inv_s for all rows + W fragment packing ----------------
__global__ __launch_bounds__(256)
void ckn1d_prep(const float* __restrict__ X, const float* __restrict__ W,
                const float* __restrict__ scale_p, float* __restrict__ ws)
{
  const int tid = threadIdx.x;
  const int bid = blockIdx.x;

  if (bid < B_ * IB_PER_B) {
    __shared__ float rowsq[IB_ROWS_ + 8];
    const int b    = bid >> 5;
    const int base = (bid & (IB_PER_B - 1)) * IB_ROWS_;
    const float scale = scale_p[0];
    const float* Xb = X + (size_t)b * LIN_ * CIN_;

    for (int r = tid; r < IB_ROWS_ + 8; r += 256) {
      int row = base + r;
      float s = 0.f;
      if (row < LIN_) {
        const float* xr = Xb + (size_t)row * CIN_;
        #pragma unroll
        for (int c = 0; c < CIN_; ++c) { float x = xr[c]; s += x * x; }
      }
      rowsq[r] = s;
    }
    __syncthreads();

    const int l0 = tid * 4;
    float e0 = 0.f;
    #pragma unroll
    for (int t = 0; t < KT_; ++t) e0 += rowsq[l0 + t];
    float e1 = e0 - rowsq[l0]     + rowsq[l0 + KT_];
    float e2 = e1 - rowsq[l0 + 1] + rowsq[l0 + 1 + KT_];
    float e3 = e2 - rowsq[l0 + 2] + rowsq[l0 + 2 + KT_];
    f32x4 iv;
    iv[0] = scale / (sqrtf(e0 + 1e-5f) + 1e-5f);
    iv[1] = scale / (sqrtf(e1 + 1e-5f) + 1e-5f);
    iv[2] = scale / (sqrtf(e2 + 1e-5f) + 1e-5f);
    iv[3] = scale / (sqrtf(e3 + 1e-5f) + 1e-5f);
    float* invp = ws + (size_t)b * LPAD_ + base + l0;
    if (base + l0 + 3 < LOUT_) {
      *(f32x4*)invp = iv;
    } else {
      #pragma unroll
      for (int u = 0; u < 4; ++u)
        if (base + l0 + u < LOUT_) invp[u] = iv[u];
    }
  } else {
    const int wv = bid - B_ * IB_PER_B;      // 0..3
    unsigned short* Wp = (unsigned short*)(ws + WP_OFF_FLOATS_);
    for (int idx = tid; idx < KSTEPS_ * 2 * 4 * 16; idx += 256) {
      int t   = idx >> 7;
      int rem = idx & 127;
      int nf  = rem >> 6;
      int q   = (rem >> 4) & 3;
      int la  = rem & 15;
      u16x8 v;
      #pragma unroll
      for (int j = 0; j < 8; ++j) {
        int r = t * 32 + q * 8 + j;
        int k = r / CPAD_;
        int c = r - k * CPAD_;
        float w = 0.f;
        if (c < CIN_ && k < KT_) w = W[(k * CIN_ + c) * F_ + wv * 32 + nf * 16 + la];
        v[j] = f2bf(w);
      }
      *(u16x8*)&Wp[(size_t)((((wv * KSTEPS_ + t) * 2 + nf) * 4 + q) * 16 + la) * 8] = v;
    }
  }
}

// ---- main: stage + MFMA + outbuf epilogue with sequential float4 stores ----
__global__ __launch_bounds__(256, 4)
void ckn1d_main(const float* __restrict__ X, const float* __restrict__ ws,
                const float* __restrict__ bias_p, float* __restrict__ Y)
{
  __shared__ __align__(16) unsigned short tileA[ROWSA_ * CPAD_]; // 6624 B
  __shared__ __align__(16) float outbuf[32 * OBST_];             // 17408 B

  const int tid  = threadIdx.x;
  const int wv   = tid >> 6;
  const int lane = tid & 63;
  const int la   = lane & 15;
  const int q    = lane >> 4;

  const int bx   = blockIdx.x;
  const int b    = bx >> 8;
  const int tile = bx & (NTILE_ - 1);
  const int l0t  = tile * TILE_L_;

  const int f0 = wv * 32 + la;
  const float bias0 = bias_p[f0];
  const float bias1 = bias_p[f0 + 16];

  const float* __restrict__ Xb   = X + (size_t)b * LIN_ * CIN_;
  const float* __restrict__ invb = ws + (size_t)b * LPAD_ + l0t;
  const unsigned short* __restrict__ Wp = (const unsigned short*)(ws + WP_OFF_FLOATS_);
  float* __restrict__ Yb = Y + (size_t)b * LOUT_ * F_;

  // ---- stage: zero pads, then 136 rows x 21 ch -> bf16 LDS ----
  for (int i = tid; i < ROWSA_ * 3; i += 256) {
    int r = i / 3;
    tileA[r * CPAD_ + CIN_ + (i - r * 3)] = 0;
  }
  for (int i = tid; i < 2 * CIN_; i += 256) {
    int r = ROWS_ + i / CIN_;
    tileA[r * CPAD_ + (i % CIN_)] = 0;
  }
  {
    const float4* src4 = (const float4*)(Xb + (size_t)l0t * CIN_);
    const int n4v = (min(ROWS_, LIN_ - l0t) * CIN_) >> 2;
    for (int i4 = tid; i4 < (ROWS_ * CIN_) / 4; i4 += 256) {
      float4 v;
      if (i4 < n4v) v = src4[i4];
      else          v = make_float4(0.f, 0.f, 0.f, 0.f);
      int base = i4 * 4;
      #pragma unroll
      for (int e = 0; e < 4; ++e) {
        int idx = base + e;
        int r = idx / CIN_;
        int c = idx - r * CIN_;
        float x = (e == 0) ? v.x : (e == 1) ? v.y : (e == 2) ? v.z : v.w;
        tileA[r * CPAD_ + c] = f2bf(x);
      }
    }
  }

  // ---- B fragments: 14 coalesced 16B loads from L2-hot Wp ----
  u16x8 bw[KSTEPS_][2];
  #pragma unroll
  for (int t = 0; t < KSTEPS_; ++t)
    #pragma unroll
    for (int nf = 0; nf < 2; ++nf)
      bw[t][nf] = *(const u16x8*)&Wp[(size_t)((((wv * KSTEPS_ + t) * 2 + nf) * 4 + q) * 16 + la) * 8];

  bar_lds();   // staging complete

  const f32x4 fzero = {0.f, 0.f, 0.f, 0.f};

  // ---- mf-pair loop: compute 32 rows, round-trip via outbuf, store seq ----
  #pragma unroll 1
  for (int mp = 0; mp < 4; ++mp) {
    f32x4 acc[2][2];   // [mf-in-pair][nf]
    #pragma unroll
    for (int mfl = 0; mfl < 2; ++mfl) {
      const int mf = mp * 2 + mfl;
      acc[mfl][0] = fzero; acc[mfl][1] = fzero;
      const unsigned short* arow = &tileA[(mf * 16 + la) * CPAD_ + q * 8];
      #pragma unroll
      for (int t = 0; t < KSTEPS_; ++t) {
        bf16x8 a = *(const bf16x8*)&arow[t * 32];
        acc[mfl][0] = __builtin_amdgcn_mfma_f32_16x16x32_bf16(
            a, __builtin_bit_cast(bf16x8, bw[t][0]), acc[mfl][0], 0, 0, 0);
        acc[mfl][1] = __builtin_amdgcn_mfma_f32_16x16x32_bf16(
            a, __builtin_bit_cast(bf16x8, bw[t][1]), acc[mfl][1], 0, 0, 0);
      }
    }

    if (mp > 0) bar_lds();   // previous pair's outbuf readers done

    // acc -> outbuf (scaled + biased). C layout: col=la, row=q*4+rg.
    #pragma unroll
    for (int mfl = 0; mfl < 2; ++mfl) {
      const int lrow0 = mfl * 16 + q * 4;          // 0..31 within pair
      const f32x4 iv4 = *(const f32x4*)&invb[mp * 32 + lrow0];
      #pragma unroll
      for (int rg = 0; rg < 4; ++rg) {
        float iv = iv4[rg];
        outbuf[(lrow0 + rg) * OBST_ + f0]      = acc[mfl][0][rg] * iv + bias0;
        outbuf[(lrow0 + rg) * OBST_ + f0 + 16] = acc[mfl][1][rg] * iv + bias1;
      }
    }
    bar_lds();   // outbuf visible

    // store: 1KB-sequential float4 per wave-instr (2 full 512B rows)
    {
      const int lg0 = l0t + mp * 32;
      #pragma unroll
      for (int it = 0; it < 4; ++it) {
        int i  = tid + it * 256;
        int r  = i >> 5;          // 0..31
        int c4 = i & 31;
        int lg = lg0 + r;
        if (lg < LOUT_) {
          float4 v = *(const float4*)&outbuf[r * OBST_ + c4 * 4];
          *(float4*)&Yb[(size_t)lg * F_ + c4 * 4] = v;
        }
      }
    }
  }
}

extern "C" void kernel_launch(void* const* d_in, const int* in_sizes, int n_in,
                              void* d_out, int out_size, void* d_ws, size_t ws_size,
                              hipStream_t stream) {
  const float* X  = (const float*)d_in[0];
  const float* W  = (const float*)d_in[1];
  const float* S  = (const float*)d_in[2];
  const float* Bi = (const float*)d_in[3];
  float* Y  = (float*)d_out;
  float* ws = (float*)d_ws;

  dim3 gprep(B_ * IB_PER_B + 4), block(256);
  ckn1d_prep<<<gprep, block, 0, stream>>>(X, W, S, ws);

  dim3 gmain(B_ * NTILE_);
  ckn1d_main<<<gmain, block, 0, stream>>>(X, ws, Bi, Y);
}